// Round 12
// baseline (237.834 us; speedup 1.0000x reference)
//
#include <hip/hip_runtime.h>
#include <cstdint>
#include <cstddef>

constexpr int V   = 128001;
constexpr int D   = 128;
constexpr int S   = 200;
constexpr int E   = 409600;
constexpr int G4  = 512;
constexpr int CAP = 8192;

typedef _Float16 h2   __attribute__((ext_vector_type(2)));
typedef _Float16 half8 __attribute__((ext_vector_type(8)));
typedef float    f32x4 __attribute__((ext_vector_type(4)));

__device__ __forceinline__ float rcp_fast(float x) {
    float r;
    asm volatile("v_rcp_f32 %0, %1" : "=v"(r) : "v"(x));
    return r;
}
__device__ __forceinline__ float sigmoid_fast(float x) {
    x = fminf(fmaxf(x, -15.f), 15.f);
    return rcp_fast(1.f + __expf(-x));
}
__device__ __forceinline__ float tanh_fast(float x) {
    x = fminf(fmaxf(x, -7.5f), 7.5f);
    float e = __expf(2.f * x);
    return (e - 1.f) * rcp_fast(e + 1.f);
}

// ---------------- degree pass + edge filter (dst % 200 == 199) ----------------
__global__ void k_deg_filter(const int* __restrict__ src, const int* __restrict__ dst,
                             int* __restrict__ deg_out, int* __restrict__ degr,
                             int* __restrict__ ecount, int2* __restrict__ elist)
{
    int e = blockIdx.x * blockDim.x + threadIdx.x;
    if (e >= E) return;
    int s = src[e], d = dst[e];
    atomicAdd(&deg_out[s], 1);
    if (d % S == S - 1) {
        int b = d / S;
        atomicAdd(&degr[b], 1);
        int p = atomicAdd(ecount, 1);
        if (p < CAP) elist[p] = make_int2(s, b);
    }
}

// ---------------- aggregate filtered edges ----------------
__global__ void k_agg(const int2* __restrict__ elist, const int* __restrict__ ecount,
                      const int* __restrict__ gnodes, const float* __restrict__ emb,
                      const int* __restrict__ deg_out, float* __restrict__ agg64)
{
    int cnt = *ecount; if (cnt > CAP) cnt = CAP;
    int idx = blockIdx.x * 2 + (threadIdx.x >> 7);
    int d   = threadIdx.x & 127;
    if (idx >= cnt) return;
    int2 eb = elist[idx];
    int s = eb.x, b = eb.y;
    int dg = deg_out[s];
    float ns = (dg > 0) ? rsqrtf((float)dg) : 0.f;
    float v = emb[(size_t)gnodes[s] * D + d] * ns;
    atomicAdd(&agg64[b * D + d], v);
}

// ---------------- h64 = relu((agg64 * n_dst) @ gW + gb), 64x128 ----------------
__global__ __launch_bounds__(512) void k_h64(const float* __restrict__ agg64,
                                             const int* __restrict__ degr,
                                             const float* __restrict__ gW,
                                             const float* __restrict__ gb,
                                             float* __restrict__ h64)
{
    __shared__ float a[64][128];
    for (int i = threadIdx.x; i < 64 * 128; i += blockDim.x) {
        int b = i >> 7;
        int dg = degr[b];
        float nd = (dg > 0) ? rsqrtf((float)dg) : 0.f;
        a[b][i & 127] = agg64[i] * nd;
    }
    __syncthreads();
    int j  = threadIdx.x & 127;
    int bg = threadIdx.x >> 7;
    float acc[16];
    float bias = gb[j];
#pragma unroll
    for (int ii = 0; ii < 16; ++ii) acc[ii] = bias;
    for (int k = 0; k < 128; ++k) {
        float w = gW[k * 128 + j];
#pragma unroll
        for (int ii = 0; ii < 16; ++ii) acc[ii] = fmaf(a[bg * 16 + ii][k], w, acc[ii]);
    }
#pragma unroll
    for (int ii = 0; ii < 16; ++ii)
        h64[(bg * 16 + ii) * 128 + j] = fmaxf(acc[ii], 0.f);
}

// ---------------- Gpre[t][u] = A[t] . Wih[u] + b1[u] + b2[u]  (64 x 512) ----------------
__global__ __launch_bounds__(256) void k_gemmG(const float* __restrict__ A,
                                               const float* __restrict__ Wih,
                                               const float* __restrict__ b1,
                                               const float* __restrict__ b2,
                                               float* __restrict__ Gpre)
{
    __shared__ float a[16][128];
    int tq = blockIdx.x >> 1;
    int ub = blockIdx.x & 1;
    for (int i = threadIdx.x; i < 16 * 128; i += 256)
        a[i >> 7][i & 127] = A[(tq * 16 + (i >> 7)) * 128 + (i & 127)];
    __syncthreads();
    int u = ub * 256 + threadIdx.x;
    float bias = b1[u] + b2[u];
    float acc[16];
#pragma unroll
    for (int t = 0; t < 16; ++t) acc[t] = bias;
    const float4* wr = reinterpret_cast<const float4*>(Wih + (size_t)u * 128);
    for (int k4 = 0; k4 < 32; ++k4) {
        float4 w4 = wr[k4];
#pragma unroll
        for (int t = 0; t < 16; ++t) {
            float4 av = *reinterpret_cast<const float4*>(&a[t][k4 * 4]);
            acc[t] += fmaf(w4.x, av.x, fmaf(w4.y, av.y, fmaf(w4.z, av.z, w4.w * av.w)));
        }
    }
#pragma unroll
    for (int t = 0; t < 16; ++t) Gpre[(tq * 16 + t) * G4 + u] = acc[t];
}

// ---------------- single-row LSTM via MFMA, weights resident in VGPRs ----------------
// R3-R7 history: every variant that streams the 512x128 weight matrix per step
// (L2, scratch, or LDS) is bound at >= 640ns/step by the stream's instruction
// cost (R7 LDS-fp16: 256 DS insts/step ~ 853ns). MFMA A-operands are the only
// per-step-free weight store: each of 8 waves holds its 64x128 fp16 slice as
// 16 half8 A-frags (64 VGPR), pinned. Per step: 4 uniform b128 B-frag reads
// (B = h replicated across all 16 N-cols -> every output col equals the dot),
// 16 mfma (fp32 accum), 4 exec-masked b128 g-writes, 2 barriers.
// Operand mapping (anchored on m89-verified C/D): lane l -> A row l&15,
// k = 8*(l>>4)+j ; B col l&15, k = 8*(l>>4)+j ; D col l&15, row 4*(l>>4)+reg.
__global__ __launch_bounds__(512, 1) void k_lstm(const float* __restrict__ Whh,   // 512 x 128
                                                 const float* __restrict__ Gpre,  // 64 x 512
                                                 const float* __restrict__ h0row, // 128
                                                 const float* __restrict__ c0row, // 128
                                                 float* __restrict__ hout)        // 64 x 128
{
    __shared__ __align__(16) _Float16 hh[2][128];
    __shared__ __align__(16) float    g_lds[512];
    const int u    = threadIdx.x;
    const int w    = u >> 6;           // wave id: owns rows 64w..64w+63
    const int l    = u & 63;
    const int lgrp = l >> 4;           // k-group / row-subgroup
    const int lrow = l & 15;           // A-row within tile, D-col

    // load A-frags: a[mt][kt] covers rows 64w+16mt+lrow, k = 32kt+8lgrp..+8
    f32x4 araw[4][4];
#pragma unroll
    for (int mt = 0; mt < 4; ++mt) {
#pragma unroll
        for (int kt = 0; kt < 4; ++kt) {
            const float* p = Whh + (size_t)(64 * w + 16 * mt + lrow) * 128 + 32 * kt + 8 * lgrp;
            float4 f0 = *reinterpret_cast<const float4*>(p);
            float4 f1 = *reinterpret_cast<const float4*>(p + 4);
            half8 hv = {(_Float16)f0.x, (_Float16)f0.y, (_Float16)f0.z, (_Float16)f0.w,
                        (_Float16)f1.x, (_Float16)f1.y, (_Float16)f1.z, (_Float16)f1.w};
            araw[mt][kt] = __builtin_bit_cast(f32x4, hv);
        }
    }
#pragma unroll
    for (int mt = 0; mt < 4; ++mt)
#pragma unroll
        for (int kt = 0; kt < 4; ++kt)
            asm volatile("" : "+v"(araw[mt][kt]));   // pin: opaque to remat/sinking

    float c = 0.f;
    if (u < 128) { hh[0][u] = (_Float16)h0row[u]; c = c0row[u]; }
    __syncthreads();

    for (int t = 0; t < 64; ++t) {
        // Gpre prefetch (phase-B operands; issued early, consumed after mfma)
        float gp0 = 0.f, gp1 = 0.f, gp2 = 0.f, gp3 = 0.f;
        if (u < 128) {
            const float* gpp = Gpre + (size_t)t * G4 + u;
            gp0 = gpp[0]; gp1 = gpp[128]; gp2 = gpp[256]; gp3 = gpp[384];
        }
        // phase A: B-frags (uniform per 16-lane group) + 16 mfma
        const _Float16* hp = &hh[t & 1][0];
        half8 b0 = *reinterpret_cast<const half8*>(hp + 8 * lgrp);
        half8 b1 = *reinterpret_cast<const half8*>(hp + 32 + 8 * lgrp);
        half8 b2 = *reinterpret_cast<const half8*>(hp + 64 + 8 * lgrp);
        half8 b3 = *reinterpret_cast<const half8*>(hp + 96 + 8 * lgrp);
        f32x4 acc[4];
#pragma unroll
        for (int mt = 0; mt < 4; ++mt) {
            acc[mt] = (f32x4){0.f, 0.f, 0.f, 0.f};
            acc[mt] = __builtin_amdgcn_mfma_f32_16x16x32_f16(
                __builtin_bit_cast(half8, araw[mt][0]), b0, acc[mt], 0, 0, 0);
            acc[mt] = __builtin_amdgcn_mfma_f32_16x16x32_f16(
                __builtin_bit_cast(half8, araw[mt][1]), b1, acc[mt], 0, 0, 0);
            acc[mt] = __builtin_amdgcn_mfma_f32_16x16x32_f16(
                __builtin_bit_cast(half8, araw[mt][2]), b2, acc[mt], 0, 0, 0);
            acc[mt] = __builtin_amdgcn_mfma_f32_16x16x32_f16(
                __builtin_bit_cast(half8, araw[mt][3]), b3, acc[mt], 0, 0, 0);
        }
        if (lrow == 0) {   // D col 0 lanes hold rows 4*lgrp+reg of each tile
#pragma unroll
            for (int mt = 0; mt < 4; ++mt)
                *reinterpret_cast<f32x4*>(&g_lds[64 * w + 16 * mt + 4 * lgrp]) = acc[mt];
        }
        __syncthreads();
        // phase B: gates + state update (2 waves)
        if (u < 128) {
            float gi = g_lds[u]       + gp0;
            float gf = g_lds[u + 128] + gp1;
            float gg = g_lds[u + 256] + gp2;
            float go = g_lds[u + 384] + gp3;
            float si = sigmoid_fast(gi);
            float sf = sigmoid_fast(gf);
            float so = sigmoid_fast(go);
            c = sf * c + si * tanh_fast(gg);
            float hn = so * tanh_fast(c);
            hh[(t + 1) & 1][u] = (_Float16)hn;
            hout[t * 128 + u] = hn;
        }
        __syncthreads();
    }
}

// ---------------- logits: 64 x 128001 ----------------
__global__ __launch_bounds__(256, 4) void k_fc(const float* __restrict__ out64,
                                               const float* __restrict__ fcW,
                                               const float* __restrict__ fcb,
                                               float* __restrict__ logits)
{
    __shared__ float ol[64][128];
    const int tid = threadIdx.x;
    for (int i = tid; i < 2048; i += 256)
        reinterpret_cast<float4*>(&ol[0][0])[i] = reinterpret_cast<const float4*>(out64)[i];
    __syncthreads();
    const int l  = tid & 63;               // v-lane
    const int q  = tid >> 6;               // b-quarter
    const int b0 = q * 16;
    const int v  = blockIdx.x * 64 + l;
    const int vc = v < V ? v : V - 1;
    const float4* W = reinterpret_cast<const float4*>(fcW + (size_t)vc * 128);
    const float fb = fcb[vc];
    float acc[16];
#pragma unroll
    for (int bb = 0; bb < 16; ++bb) acc[bb] = fb;
    float4 w0 = W[0], w1 = W[1];
    for (int k4 = 0; k4 < 32; ++k4) {
        float4 wn = (k4 + 2 < 32) ? W[k4 + 2] : w1;   // depth-2 prefetch
#pragma unroll
        for (int bb = 0; bb < 16; ++bb) {
            float4 a = *reinterpret_cast<const float4*>(&ol[b0 + bb][k4 * 4]);  // uniform broadcast
            acc[bb] += w0.x * a.x + w0.y * a.y + w0.z * a.z + w0.w * a.w;
        }
        w0 = w1; w1 = wn;
    }
    if (v < V) {
#pragma unroll
        for (int bb = 0; bb < 16; ++bb)
            logits[(size_t)(b0 + bb) * V + v] = acc[bb];
    }
}

extern "C" void kernel_launch(void* const* d_in, const int* in_sizes, int n_in,
                              void* d_out, int out_size, void* d_ws, size_t ws_size,
                              hipStream_t stream)
{
    const int*   gnodes = (const int*)d_in[0];
    const int*   src    = (const int*)d_in[1];
    const int*   dst    = (const int*)d_in[2];
    const float* emb    = (const float*)d_in[3];
    const float* gW     = (const float*)d_in[4];
    const float* gb     = (const float*)d_in[5];
    const float* Wih0   = (const float*)d_in[6];
    const float* Whh0   = (const float*)d_in[7];
    const float* bih0   = (const float*)d_in[8];
    const float* bhh0   = (const float*)d_in[9];
    const float* Wih1   = (const float*)d_in[10];
    const float* Whh1   = (const float*)d_in[11];
    const float* bih1   = (const float*)d_in[12];
    const float* bhh1   = (const float*)d_in[13];
    const float* fcW    = (const float*)d_in[14];
    const float* fcb    = (const float*)d_in[15];
    const float* h0     = (const float*)d_in[16];  // (2, 200, 128)
    const float* c0     = (const float*)d_in[17];

    char* ws = (char*)d_ws;
    int*   deg_out = (int*)(ws + 0);          // 12800 ints
    int*   degr    = (int*)(ws + 51200);      // 64 ints
    int*   ecount  = (int*)(ws + 51456);      // 1 int
    float* agg64   = (float*)(ws + 51712);    // 64*128 -> zero region ends at 84480
    int2*  elist   = (int2*)(ws + 84480);     // CAP entries (64 KB) -> 150016
    float* h64     = (float*)(ws + 150016);   // 32 KB -> 182784
    float* Gpre    = (float*)(ws + 182784);   // 128 KB -> 313856 (shared by both layers)
    float* h1out   = (float*)(ws + 313856);   // 32 KB -> 346624
    float* out64   = (float*)(ws + 346624);   // 32 KB -> 379392
    float* logits  = (float*)d_out;

    hipMemsetAsync(ws, 0, 84480, stream);     // deg_out, degr, ecount, agg64

    k_deg_filter<<<E / 256, 256, 0, stream>>>(src, dst, deg_out, degr, ecount, elist);
    k_agg<<<CAP / 2, 256, 0, stream>>>(elist, ecount, gnodes, emb, deg_out, agg64);
    k_h64<<<1, 512, 0, stream>>>(agg64, degr, gW, gb, h64);

    k_gemmG<<<8, 256, 0, stream>>>(h64, Wih0, bih0, bhh0, Gpre);
    k_lstm<<<1, 512, 0, stream>>>(Whh0, Gpre, h0 + 199 * 128, c0 + 199 * 128, h1out);
    k_gemmG<<<8, 256, 0, stream>>>(h1out, Wih1, bih1, bhh1, Gpre);
    k_lstm<<<1, 512, 0, stream>>>(Whh1, Gpre, h0 + (200 + 199) * 128, c0 + (200 + 199) * 128, out64);

    k_fc<<<(V + 63) / 64, 256, 0, stream>>>(out64, fcW, fcb, logits);
}

// Round 15
// 214.495 us; speedup vs baseline: 1.1088x; 1.1088x over previous
//
#include <hip/hip_runtime.h>
#include <cstdint>
#include <cstddef>

constexpr int V   = 128001;
constexpr int D   = 128;
constexpr int S   = 200;
constexpr int E   = 409600;
constexpr int G4  = 512;
constexpr int CAP = 8192;

typedef _Float16 half8 __attribute__((ext_vector_type(8)));
typedef float    f32x4 __attribute__((ext_vector_type(4)));

__device__ __forceinline__ float rcp_fast(float x) {
    float r;
    asm volatile("v_rcp_f32 %0, %1" : "=v"(r) : "v"(x));
    return r;
}
__device__ __forceinline__ float sigmoid_fast(float x) {
    x = fminf(fmaxf(x, -15.f), 15.f);
    return rcp_fast(1.f + __expf(-x));
}
__device__ __forceinline__ float tanh_fast(float x) {
    x = fminf(fmaxf(x, -7.5f), 7.5f);
    float e = __expf(2.f * x);
    return (e - 1.f) * rcp_fast(e + 1.f);
}
__device__ __forceinline__ half8 cvt_h8(float4 f0, float4 f1) {
    half8 h = {(_Float16)f0.x, (_Float16)f0.y, (_Float16)f0.z, (_Float16)f0.w,
               (_Float16)f1.x, (_Float16)f1.y, (_Float16)f1.z, (_Float16)f1.w};
    return h;
}
// split-fp16: hi = fp16(x), lo = fp16(x - hi); hi+lo carries ~22 mantissa bits
__device__ __forceinline__ void split_h8(float4 f0, float4 f1, half8& hi, half8& lo) {
    hi = cvt_h8(f0, f1);
    half8 l = {(_Float16)(f0.x - (float)hi[0]), (_Float16)(f0.y - (float)hi[1]),
               (_Float16)(f0.z - (float)hi[2]), (_Float16)(f0.w - (float)hi[3]),
               (_Float16)(f1.x - (float)hi[4]), (_Float16)(f1.y - (float)hi[5]),
               (_Float16)(f1.z - (float)hi[6]), (_Float16)(f1.w - (float)hi[7])};
    lo = l;
}

// ---------------- degree pass + edge filter (dst % 200 == 199) ----------------
__global__ void k_deg_filter(const int* __restrict__ src, const int* __restrict__ dst,
                             int* __restrict__ deg_out, int* __restrict__ degr,
                             int* __restrict__ ecount, int2* __restrict__ elist)
{
    int e = blockIdx.x * blockDim.x + threadIdx.x;
    if (e >= E) return;
    int s = src[e], d = dst[e];
    atomicAdd(&deg_out[s], 1);
    if (d % S == S - 1) {
        int b = d / S;
        atomicAdd(&degr[b], 1);
        int p = atomicAdd(ecount, 1);
        if (p < CAP) elist[p] = make_int2(s, b);
    }
}

// ---------------- aggregate filtered edges ----------------
__global__ void k_agg(const int2* __restrict__ elist, const int* __restrict__ ecount,
                      const int* __restrict__ gnodes, const float* __restrict__ emb,
                      const int* __restrict__ deg_out, float* __restrict__ agg64)
{
    int cnt = *ecount; if (cnt > CAP) cnt = CAP;
    int idx = blockIdx.x * 2 + (threadIdx.x >> 7);
    int d   = threadIdx.x & 127;
    if (idx >= cnt) return;
    int2 eb = elist[idx];
    int s = eb.x, b = eb.y;
    int dg = deg_out[s];
    float ns = (dg > 0) ? rsqrtf((float)dg) : 0.f;
    float v = emb[(size_t)gnodes[s] * D + d] * ns;
    atomicAdd(&agg64[b * D + d], v);
}

// ---------------- h64 = relu((agg64 * n_dst) @ gW + gb), 64x128 ----------------
__global__ __launch_bounds__(512) void k_h64(const float* __restrict__ agg64,
                                             const int* __restrict__ degr,
                                             const float* __restrict__ gW,
                                             const float* __restrict__ gb,
                                             float* __restrict__ h64)
{
    __shared__ float a[64][128];
    for (int i = threadIdx.x; i < 64 * 128; i += blockDim.x) {
        int b = i >> 7;
        int dg = degr[b];
        float nd = (dg > 0) ? rsqrtf((float)dg) : 0.f;
        a[b][i & 127] = agg64[i] * nd;
    }
    __syncthreads();
    int j  = threadIdx.x & 127;
    int bg = threadIdx.x >> 7;
    float acc[16];
    float bias = gb[j];
#pragma unroll
    for (int ii = 0; ii < 16; ++ii) acc[ii] = bias;
    for (int k = 0; k < 128; ++k) {
        float w = gW[k * 128 + j];
#pragma unroll
        for (int ii = 0; ii < 16; ++ii) acc[ii] = fmaf(a[bg * 16 + ii][k], w, acc[ii]);
    }
#pragma unroll
    for (int ii = 0; ii < 16; ++ii)
        h64[(bg * 16 + ii) * 128 + j] = fmaxf(acc[ii], 0.f);
}

// ---------------- Gpre[t][u] = A[t] . Wih[u] + b1[u] + b2[u]  (64 x 512) ----------------
__global__ __launch_bounds__(256) void k_gemmG(const float* __restrict__ A,
                                               const float* __restrict__ Wih,
                                               const float* __restrict__ b1,
                                               const float* __restrict__ b2,
                                               float* __restrict__ Gpre)
{
    __shared__ float a[16][128];
    int tq = blockIdx.x >> 1;
    int ub = blockIdx.x & 1;
    for (int i = threadIdx.x; i < 16 * 128; i += 256)
        a[i >> 7][i & 127] = A[(tq * 16 + (i >> 7)) * 128 + (i & 127)];
    __syncthreads();
    int u = ub * 256 + threadIdx.x;
    float bias = b1[u] + b2[u];
    float acc[16];
#pragma unroll
    for (int t = 0; t < 16; ++t) acc[t] = bias;
    const float4* wr = reinterpret_cast<const float4*>(Wih + (size_t)u * 128);
    for (int k4 = 0; k4 < 32; ++k4) {
        float4 w4 = wr[k4];
#pragma unroll
        for (int t = 0; t < 16; ++t) {
            float4 av = *reinterpret_cast<const float4*>(&a[t][k4 * 4]);
            acc[t] += fmaf(w4.x, av.x, fmaf(w4.y, av.y, fmaf(w4.z, av.z, w4.w * av.w)));
        }
    }
#pragma unroll
    for (int t = 0; t < 16; ++t) Gpre[(tq * 16 + t) * G4 + u] = acc[t];
}

// ---------------- single-row LSTM via MFMA, weights resident in VGPRs (R12, works) ----------------
__global__ __launch_bounds__(512, 1) void k_lstm(const float* __restrict__ Whh,   // 512 x 128
                                                 const float* __restrict__ Gpre,  // 64 x 512
                                                 const float* __restrict__ h0row, // 128
                                                 const float* __restrict__ c0row, // 128
                                                 float* __restrict__ hout)        // 64 x 128
{
    __shared__ __align__(16) _Float16 hh[2][128];
    __shared__ __align__(16) float    g_lds[512];
    const int u    = threadIdx.x;
    const int w    = u >> 6;
    const int l    = u & 63;
    const int lgrp = l >> 4;
    const int lrow = l & 15;

    f32x4 araw[4][4];
#pragma unroll
    for (int mt = 0; mt < 4; ++mt) {
#pragma unroll
        for (int kt = 0; kt < 4; ++kt) {
            const float* p = Whh + (size_t)(64 * w + 16 * mt + lrow) * 128 + 32 * kt + 8 * lgrp;
            float4 f0 = *reinterpret_cast<const float4*>(p);
            float4 f1 = *reinterpret_cast<const float4*>(p + 4);
            araw[mt][kt] = __builtin_bit_cast(f32x4, cvt_h8(f0, f1));
        }
    }
#pragma unroll
    for (int mt = 0; mt < 4; ++mt)
#pragma unroll
        for (int kt = 0; kt < 4; ++kt)
            asm volatile("" : "+v"(araw[mt][kt]));   // pin: opaque to remat/sinking

    float c = 0.f;
    if (u < 128) { hh[0][u] = (_Float16)h0row[u]; c = c0row[u]; }
    __syncthreads();

    for (int t = 0; t < 64; ++t) {
        float gp0 = 0.f, gp1 = 0.f, gp2 = 0.f, gp3 = 0.f;
        if (u < 128) {
            const float* gpp = Gpre + (size_t)t * G4 + u;
            gp0 = gpp[0]; gp1 = gpp[128]; gp2 = gpp[256]; gp3 = gpp[384];
        }
        const _Float16* hp = &hh[t & 1][0];
        half8 b0 = *reinterpret_cast<const half8*>(hp + 8 * lgrp);
        half8 b1 = *reinterpret_cast<const half8*>(hp + 32 + 8 * lgrp);
        half8 b2 = *reinterpret_cast<const half8*>(hp + 64 + 8 * lgrp);
        half8 b3 = *reinterpret_cast<const half8*>(hp + 96 + 8 * lgrp);
        f32x4 acc[4];
#pragma unroll
        for (int mt = 0; mt < 4; ++mt) {
            acc[mt] = (f32x4){0.f, 0.f, 0.f, 0.f};
            acc[mt] = __builtin_amdgcn_mfma_f32_16x16x32_f16(
                __builtin_bit_cast(half8, araw[mt][0]), b0, acc[mt], 0, 0, 0);
            acc[mt] = __builtin_amdgcn_mfma_f32_16x16x32_f16(
                __builtin_bit_cast(half8, araw[mt][1]), b1, acc[mt], 0, 0, 0);
            acc[mt] = __builtin_amdgcn_mfma_f32_16x16x32_f16(
                __builtin_bit_cast(half8, araw[mt][2]), b2, acc[mt], 0, 0, 0);
            acc[mt] = __builtin_amdgcn_mfma_f32_16x16x32_f16(
                __builtin_bit_cast(half8, araw[mt][3]), b3, acc[mt], 0, 0, 0);
        }
        if (lrow == 0) {
#pragma unroll
            for (int mt = 0; mt < 4; ++mt)
                *reinterpret_cast<f32x4*>(&g_lds[64 * w + 16 * mt + 4 * lgrp]) = acc[mt];
        }
        __syncthreads();
        if (u < 128) {
            float gi = g_lds[u]       + gp0;
            float gf = g_lds[u + 128] + gp1;
            float gg = g_lds[u + 256] + gp2;
            float go = g_lds[u + 384] + gp3;
            float si = sigmoid_fast(gi);
            float sf = sigmoid_fast(gf);
            float so = sigmoid_fast(go);
            c = sf * c + si * tanh_fast(gg);
            float hn = so * tanh_fast(c);
            hh[(t + 1) & 1][u] = (_Float16)hn;
            hout[t * 128 + u] = hn;
        }
        __syncthreads();
    }
}

// ---------------- logits via MFMA + split-fp16: 64 x 128001 x 128, NO LDS ----------------
// R14 post-mortem: R13/R14 had BIT-IDENTICAL absmax (2.193451e-05) across
// different numerics -> the max-error element was never written. Grid covered
// only 8000 of ceil(128001/16)=8001 v-tiles; column v=128000 stayed 0 (its ref
// magnitude = the reported absmax). Fix: 1001 blocks. Split-fp16 numerics
// (Ah*Bh + Al*Bh + Ah*Bl, fp32 accum) were already at ~5e-7 level.
__global__ __launch_bounds__(256, 2) void k_fc(const float* __restrict__ out64,
                                               const float* __restrict__ fcW,
                                               const float* __restrict__ fcb,
                                               float* __restrict__ logits)
{
    const int tid  = threadIdx.x;
    const int w    = tid >> 6;
    const int l    = tid & 63;
    const int lgrp = l >> 4;
    const int lrow = l & 15;

    // A-frags: out64 (64 b x 128 k) -> split fp16, resident (128 VGPR)
    f32x4 ah[4][4], al[4][4];
#pragma unroll
    for (int mt = 0; mt < 4; ++mt) {
#pragma unroll
        for (int kt = 0; kt < 4; ++kt) {
            const float* p = out64 + (size_t)(16 * mt + lrow) * 128 + 32 * kt + 8 * lgrp;
            float4 f0 = *reinterpret_cast<const float4*>(p);
            float4 f1 = *reinterpret_cast<const float4*>(p + 4);
            half8 hi, lo;
            split_h8(f0, f1, hi, lo);
            ah[mt][kt] = __builtin_bit_cast(f32x4, hi);
            al[mt][kt] = __builtin_bit_cast(f32x4, lo);
        }
    }
#pragma unroll
    for (int mt = 0; mt < 4; ++mt)
#pragma unroll
        for (int kt = 0; kt < 4; ++kt) {
            asm volatile("" : "+v"(ah[mt][kt]));
            asm volatile("" : "+v"(al[mt][kt]));
        }

#pragma unroll
    for (int i = 0; i < 2; ++i) {
        int vt = blockIdx.x * 8 + w * 2 + i;        // 16-wide v-tile index
        int v0 = vt * 16;
        if (v0 >= V) break;                          // wave-uniform
        int v  = v0 + lrow;
        int vc = v < V ? v : V - 1;
        // B-frags: fcW row vc, split fp16 (32B/lane, row read once)
        half8 bh[4], bl[4];
#pragma unroll
        for (int kt = 0; kt < 4; ++kt) {
            const float* p = fcW + (size_t)vc * 128 + 32 * kt + 8 * lgrp;
            float4 f0 = *reinterpret_cast<const float4*>(p);
            float4 f1 = *reinterpret_cast<const float4*>(p + 4);
            split_h8(f0, f1, bh[kt], bl[kt]);
        }
        float fb = fcb[vc];
        f32x4 acc[4];
#pragma unroll
        for (int mt = 0; mt < 4; ++mt) {
            acc[mt] = (f32x4){fb, fb, fb, fb};
#pragma unroll
            for (int kt = 0; kt < 4; ++kt) {
                acc[mt] = __builtin_amdgcn_mfma_f32_16x16x32_f16(
                    __builtin_bit_cast(half8, ah[mt][kt]), bh[kt], acc[mt], 0, 0, 0);
                acc[mt] = __builtin_amdgcn_mfma_f32_16x16x32_f16(
                    __builtin_bit_cast(half8, al[mt][kt]), bh[kt], acc[mt], 0, 0, 0);
                acc[mt] = __builtin_amdgcn_mfma_f32_16x16x32_f16(
                    __builtin_bit_cast(half8, ah[mt][kt]), bl[kt], acc[mt], 0, 0, 0);
            }
        }
        if (v < V) {
#pragma unroll
            for (int mt = 0; mt < 4; ++mt)
#pragma unroll
                for (int r = 0; r < 4; ++r)
                    logits[(size_t)(16 * mt + 4 * lgrp + r) * V + v] = acc[mt][r];
        }
    }
}

extern "C" void kernel_launch(void* const* d_in, const int* in_sizes, int n_in,
                              void* d_out, int out_size, void* d_ws, size_t ws_size,
                              hipStream_t stream)
{
    const int*   gnodes = (const int*)d_in[0];
    const int*   src    = (const int*)d_in[1];
    const int*   dst    = (const int*)d_in[2];
    const float* emb    = (const float*)d_in[3];
    const float* gW     = (const float*)d_in[4];
    const float* gb     = (const float*)d_in[5];
    const float* Wih0   = (const float*)d_in[6];
    const float* Whh0   = (const float*)d_in[7];
    const float* bih0   = (const float*)d_in[8];
    const float* bhh0   = (const float*)d_in[9];
    const float* Wih1   = (const float*)d_in[10];
    const float* Whh1   = (const float*)d_in[11];
    const float* bih1   = (const float*)d_in[12];
    const float* bhh1   = (const float*)d_in[13];
    const float* fcW    = (const float*)d_in[14];
    const float* fcb    = (const float*)d_in[15];
    const float* h0     = (const float*)d_in[16];  // (2, 200, 128)
    const float* c0     = (const float*)d_in[17];

    char* ws = (char*)d_ws;
    int*   deg_out = (int*)(ws + 0);          // 12800 ints
    int*   degr    = (int*)(ws + 51200);      // 64 ints
    int*   ecount  = (int*)(ws + 51456);      // 1 int
    float* agg64   = (float*)(ws + 51712);    // 64*128 -> zero region ends at 84480
    int2*  elist   = (int2*)(ws + 84480);     // CAP entries (64 KB) -> 150016
    float* h64     = (float*)(ws + 150016);   // 32 KB -> 182784
    float* Gpre    = (float*)(ws + 182784);   // 128 KB -> 313856 (shared by both layers)
    float* h1out   = (float*)(ws + 313856);   // 32 KB -> 346624
    float* out64   = (float*)(ws + 346624);   // 32 KB -> 379392
    float* logits  = (float*)d_out;

    hipMemsetAsync(ws, 0, 84480, stream);     // deg_out, degr, ecount, agg64

    k_deg_filter<<<E / 256, 256, 0, stream>>>(src, dst, deg_out, degr, ecount, elist);
    k_agg<<<CAP / 2, 256, 0, stream>>>(elist, ecount, gnodes, emb, deg_out, agg64);
    k_h64<<<1, 512, 0, stream>>>(agg64, degr, gW, gb, h64);

    k_gemmG<<<8, 256, 0, stream>>>(h64, Wih0, bih0, bhh0, Gpre);
    k_lstm<<<1, 512, 0, stream>>>(Whh0, Gpre, h0 + 199 * 128, c0 + 199 * 128, h1out);
    k_gemmG<<<8, 256, 0, stream>>>(h1out, Wih1, bih1, bhh1, Gpre);
    k_lstm<<<1, 512, 0, stream>>>(Whh1, Gpre, h0 + (200 + 199) * 128, c0 + (200 + 199) * 128, out64);

    // ceil(ceil(V/16)/8) = 1001 blocks: covers all 8001 v-tiles incl. v=128000
    k_fc<<<1001, 256, 0, stream>>>(out64, fcW, fcb, logits);
}